// Round 2
// baseline (529.312 us; speedup 1.0000x reference)
//
#include <hip/hip_runtime.h>
#include <hip/hip_bf16.h>
#include <stdint.h>

#define D_MODEL 1024
#define NUM_HEADS 16
#define DK 64
#define BATCH 4
#define SEQ 2048
#define MTOT (BATCH * SEQ)   // 8192 tokens

typedef unsigned short u16;
typedef __bf16 bf16x8 __attribute__((ext_vector_type(8)));
typedef float f32x4 __attribute__((ext_vector_type(4)));

__device__ __forceinline__ u16 f2bf(float f) {
  union { float f; unsigned u; } c; c.f = f;
  unsigned u = c.u + 0x7fffu + ((c.u >> 16) & 1u);   // RNE
  return (u16)(u >> 16);
}

// async global->LDS, 16B per lane. lds must be wave-uniform (HW: readfirstlane + lane*16).
__device__ __forceinline__ void async16(void* g, void* lds) {
  __builtin_amdgcn_global_load_lds(
      (__attribute__((address_space(1))) void*)g,
      (__attribute__((address_space(3))) void*)lds,
      16, 0, 0);
}

// f32 -> bf16 copy, 8 elements/thread (n must be a multiple of 8)
__global__ __launch_bounds__(256)
void cvt_f32_bf16(const float* __restrict__ s, u16* __restrict__ d, int n) {
  const int i = (blockIdx.x * 256 + threadIdx.x) * 8;
  if (i >= n) return;
  const float4 a = *(const float4*)(s + i);
  const float4 b = *(const float4*)(s + i + 4);
  ushort4 lo = make_ushort4(f2bf(a.x), f2bf(a.y), f2bf(a.z), f2bf(a.w));
  ushort4 hi = make_ushort4(f2bf(b.x), f2bf(b.y), f2bf(b.z), f2bf(b.w));
  *(ushort4*)(d + i) = lo;
  *(ushort4*)(d + i + 4) = hi;
}

// C = A @ W^T + bias.  A:[M,1024] bf16, W:[1024,1024] bf16 stored [n][k], bias:[1024] f32.
// VT_OUT=false: C[token][chan] ([B,S,D] flat).
// VT_OUT=true : C written transposed per head: [B][H][DK][SEQ] (attention V operand).
// F32_OUT=true: C is float* ([B,S,D] flat).
template <bool VT_OUT, bool F32_OUT>
__global__ __launch_bounds__(256, 2)
void gemm_bt_bias(const u16* __restrict__ A, const u16* __restrict__ W,
                  const float* __restrict__ bias, void* __restrict__ Cv)
{
  __shared__ u16 As[128 * 32];
  __shared__ u16 Bs[128 * 32];
  const int t = threadIdx.x;
  const int w = t >> 6, l = t & 63;
  const int quad = l >> 4, lane16 = l & 15;
  const int m0 = blockIdx.x * 128;
  const int n0 = blockIdx.y * 128;
  const int wm = (w >> 1) * 64, wn = (w & 1) * 64;

  // staging coords: thread t covers tile elems [t*8, t*8+8) (+2048 on pass 2)
  const int srow = t >> 2;            // 0..63
  const int scol = (t & 3) * 8;       // 0,8,16,24
  const u16* Ag = A + (long)(m0 + srow) * D_MODEL + scol;
  const u16* Wg = W + (long)(n0 + srow) * D_MODEL + scol;
  u16* As_w = As + w * 512;           // w*1024 bytes
  u16* Bs_w = Bs + w * 512;

  f32x4 acc[4][4] = {};

  for (int k0 = 0; k0 < D_MODEL; k0 += 32) {
    __syncthreads();
    async16((void*)(Ag + k0), As_w);
    async16((void*)(Ag + 64 * D_MODEL + k0), As_w + 2048);
    async16((void*)(Wg + k0), Bs_w);
    async16((void*)(Wg + 64 * D_MODEL + k0), Bs_w + 2048);
    __syncthreads();

    bf16x8 af[4], bfr[4];
#pragma unroll
    for (int i = 0; i < 4; ++i)
      af[i] = *(const bf16x8*)&As[(wm + i * 16 + lane16) * 32 + quad * 8];
#pragma unroll
    for (int i = 0; i < 4; ++i)
      bfr[i] = *(const bf16x8*)&Bs[(wn + i * 16 + lane16) * 32 + quad * 8];
#pragma unroll
    for (int i = 0; i < 4; ++i)
#pragma unroll
      for (int jn = 0; jn < 4; ++jn)
        acc[i][jn] = __builtin_amdgcn_mfma_f32_16x16x32_bf16(af[i], bfr[jn], acc[i][jn], 0, 0, 0);
  }

  // epilogue: C/D layout per 16x16 tile: col = lane16, row = quad*4 + r
#pragma unroll
  for (int jn = 0; jn < 4; ++jn) {
    const int col = n0 + wn + jn * 16 + lane16;
    const float bb = bias[col];
#pragma unroll
    for (int i = 0; i < 4; ++i) {
      const int rbase = m0 + wm + i * 16 + quad * 4;
#pragma unroll
      for (int r = 0; r < 4; ++r) {
        const float v = acc[i][jn][r] + bb;
        const int row = rbase + r;
        if (F32_OUT) {
          ((float*)Cv)[(long)row * D_MODEL + col] = v;
        } else if (VT_OUT) {
          const int b = row >> 11, s = row & 2047;       // SEQ = 2048
          const int h = col >> 6, dk = col & 63;         // DK = 64
          ((u16*)Cv)[(((long)b * NUM_HEADS + h) * DK + dk) * SEQ + s] = f2bf(v);
        } else {
          ((u16*)Cv)[(long)row * D_MODEL + col] = f2bf(v);
        }
      }
    }
  }
}

// Causal flash attention. Q,K: [B,S,D] bf16 (head h at cols h*64..).
// Vt: [B][H][DK][SEQ] bf16 (pre-transposed).  O: [B,S,D] bf16.
// Grid: (S/128, B*H). Block: 256. Wave w owns q-rows [qt*128+w*32, +32).
__global__ __launch_bounds__(256, 2)
void attn_causal(const u16* __restrict__ Q, const u16* __restrict__ K,
                 const u16* __restrict__ Vt_g, u16* __restrict__ O)
{
  __shared__ u16 Qs[128 * 64];   // [qrow][dk]
  __shared__ u16 Ks[128 * 64];   // [krow][dk]
  __shared__ u16 Vt[64 * 128];   // [dk][krow]
  __shared__ u16 Ps[4 * 32 * 128]; // per-wave P strips [32][128]

  const int t = threadIdx.x;
  const int w = t >> 6, l = t & 63;
  const int quad = l >> 4, lane16 = l & 15;
  const int qt = gridDim.x - 1 - blockIdx.x;   // heavy (long-loop) blocks first
  const int bh = blockIdx.y;
  const int b = bh >> 4, h = bh & 15;

  const long qkbase = (long)b * SEQ * D_MODEL + (long)h * DK;
  const long vbase  = ((long)b * NUM_HEADS + h) * DK * (long)SEQ;

  // --- stage Q tile (128x64), 4 passes of 256 lanes * 16B
  const int qrow = t >> 3, qcol = (t & 7) * 8;       // for Q/K tiles (stride 64)
  const int vrow = t >> 4, vcol = (t & 15) * 8;      // for Vt tile  (stride 128)
#pragma unroll
  for (int p = 0; p < 4; ++p)
    async16((void*)(Q + qkbase + (long)(qt * 128 + p * 32 + qrow) * D_MODEL + qcol),
            Qs + p * 2048 + w * 512);

  f32x4 oacc[2][4] = {};
  float mrow[2][4], lrow[2][4];
#pragma unroll
  for (int im = 0; im < 2; ++im)
#pragma unroll
    for (int r = 0; r < 4; ++r) { mrow[im][r] = -1e30f; lrow[im][r] = 0.f; }

  const int wq = w * 32;
  u16* Psw = Ps + w * 4096;

  for (int j = 0; j <= qt; ++j) {
    __syncthreads();   // prior iter's LDS reads done (also drains Q stage on j=0)
#pragma unroll
    for (int p = 0; p < 4; ++p)
      async16((void*)(K + qkbase + (long)(j * 128 + p * 32 + qrow) * D_MODEL + qcol),
              Ks + p * 2048 + w * 512);
#pragma unroll
    for (int p = 0; p < 4; ++p)
      async16((void*)(Vt_g + vbase + (long)(p * 16 + vrow) * SEQ + j * 128 + vcol),
              Vt + p * 2048 + w * 512);
    __syncthreads();

    // --- S = Q K^T (rows wq..wq+32 x 128 cols), k-dim = dk = 64 (2 MFMA steps)
    f32x4 sc[2][8] = {};
    bf16x8 aq[2][2];
#pragma unroll
    for (int im = 0; im < 2; ++im)
#pragma unroll
      for (int ks = 0; ks < 2; ++ks)
        aq[im][ks] = *(const bf16x8*)&Qs[(wq + im * 16 + lane16) * 64 + ks * 32 + quad * 8];
#pragma unroll
    for (int nt = 0; nt < 8; ++nt) {
#pragma unroll
      for (int ks = 0; ks < 2; ++ks) {
        const bf16x8 bk = *(const bf16x8*)&Ks[(nt * 16 + lane16) * 64 + ks * 32 + quad * 8];
#pragma unroll
        for (int im = 0; im < 2; ++im)
          sc[im][nt] = __builtin_amdgcn_mfma_f32_16x16x32_bf16(aq[im][ks], bk, sc[im][nt], 0, 0, 0);
      }
    }

    // --- scale + causal mask (only diagonal KV tile needs masking)
    const bool diag = (j == qt);
#pragma unroll
    for (int im = 0; im < 2; ++im)
#pragma unroll
      for (int nt = 0; nt < 8; ++nt)
#pragma unroll
        for (int r = 0; r < 4; ++r) {
          float s = sc[im][nt][r] * 0.125f;   // 1/sqrt(64)
          if (diag && (nt * 16 + lane16 > wq + im * 16 + quad * 4 + r)) s = -1e30f;
          sc[im][nt][r] = s;
        }

    // --- online softmax per 16-row block
#pragma unroll
    for (int im = 0; im < 2; ++im) {
      float vmax[4];
#pragma unroll
      for (int r = 0; r < 4; ++r) vmax[r] = sc[im][0][r];
#pragma unroll
      for (int nt = 1; nt < 8; ++nt)
#pragma unroll
        for (int r = 0; r < 4; ++r) vmax[r] = fmaxf(vmax[r], sc[im][nt][r]);
#pragma unroll
      for (int off = 1; off < 16; off <<= 1)
#pragma unroll
        for (int r = 0; r < 4; ++r) vmax[r] = fmaxf(vmax[r], __shfl_xor(vmax[r], off, 16));

      float alpha[4];
#pragma unroll
      for (int r = 0; r < 4; ++r) {
        const float mnew = fmaxf(mrow[im][r], vmax[r]);
        alpha[r] = __expf(mrow[im][r] - mnew);
        mrow[im][r] = mnew;
      }
      float rsum[4] = {0.f, 0.f, 0.f, 0.f};
#pragma unroll
      for (int nt = 0; nt < 8; ++nt)
#pragma unroll
        for (int r = 0; r < 4; ++r) {
          const float p = __expf(sc[im][nt][r] - mrow[im][r]);
          rsum[r] += p;
          Psw[(im * 16 + quad * 4 + r) * 128 + nt * 16 + lane16] = f2bf(p);
        }
#pragma unroll
      for (int off = 1; off < 16; off <<= 1)
#pragma unroll
        for (int r = 0; r < 4; ++r) rsum[r] += __shfl_xor(rsum[r], off, 16);
#pragma unroll
      for (int r = 0; r < 4; ++r) lrow[im][r] = lrow[im][r] * alpha[r] + rsum[r];
#pragma unroll
      for (int nd = 0; nd < 4; ++nd)
#pragma unroll
        for (int r = 0; r < 4; ++r) oacc[im][nd][r] *= alpha[r];
    }
    __syncthreads();   // drain Ps writes before A-layout reads

    // --- O += P V  (P: 32x128 A-layout from LDS; V^T rows = dk, k = key contiguous)
#pragma unroll
    for (int kt = 0; kt < 4; ++kt) {
      bf16x8 ap[2];
#pragma unroll
      for (int im = 0; im < 2; ++im)
        ap[im] = *(const bf16x8*)&Psw[(im * 16 + lane16) * 128 + kt * 32 + quad * 8];
#pragma unroll
      for (int nd = 0; nd < 4; ++nd) {
        const bf16x8 bv = *(const bf16x8*)&Vt[(nd * 16 + lane16) * 128 + kt * 32 + quad * 8];
#pragma unroll
        for (int im = 0; im < 2; ++im)
          oacc[im][nd] = __builtin_amdgcn_mfma_f32_16x16x32_bf16(ap[im], bv, oacc[im][nd], 0, 0, 0);
      }
    }
  }

  // --- epilogue: O / l, write [B,S,D]
#pragma unroll
  for (int im = 0; im < 2; ++im)
#pragma unroll
    for (int nd = 0; nd < 4; ++nd) {
      const int col = h * DK + nd * 16 + lane16;
#pragma unroll
      for (int r = 0; r < 4; ++r) {
        const int row = qt * 128 + wq + im * 16 + quad * 4 + r;
        O[((long)b * SEQ + row) * D_MODEL + col] = f2bf(oacc[im][nd][r] / lrow[im][r]);
      }
    }
}

extern "C" void kernel_launch(void* const* d_in, const int* in_sizes, int n_in,
                              void* d_out, int out_size, void* d_ws, size_t ws_size,
                              hipStream_t stream) {
  const float* q  = (const float*)d_in[0];
  const float* k  = (const float*)d_in[1];
  const float* v  = (const float*)d_in[2];
  // d_in[3]: causal mask (int32 tril) — semantics hardcoded in attn_causal
  const float* Wq = (const float*)d_in[4];
  const float* bq = (const float*)d_in[5];
  const float* Wk = (const float*)d_in[6];
  const float* bk = (const float*)d_in[7];
  const float* Wv = (const float*)d_in[8];
  const float* bv = (const float*)d_in[9];
  const float* Wo = (const float*)d_in[10];
  const float* bo = (const float*)d_in[11];
  float* out = (float*)d_out;

  const size_t NT = (size_t)MTOT * D_MODEL;     // 8,388,608
  const size_t NW = (size_t)D_MODEL * D_MODEL;  // 1,048,576

  // ws (u16 elems): [0:NT) qb -> later Vpt ; [NT:2NT) kb -> later Xp ; [2NT:3NT) vb ;
  //                 [3NT ..) Wqb,Wkb,Wvb,Wob.   Total 3*NT+4*NW elems = 58.7 MB.
  u16* w0  = (u16*)d_ws;
  u16* qb  = w0;
  u16* kb  = w0 + NT;
  u16* vb  = w0 + 2 * NT;
  u16* Wqb = w0 + 3 * NT;
  u16* Wkb = Wqb + NW;
  u16* Wvb = Wqb + 2 * NW;
  u16* Wob = Wqb + 3 * NW;
  // d_out (32 MB f32) doubles as scratch for the bf16 Q/K projections.
  u16* Qp  = (u16*)d_out;        // [B,S,D] bf16, 16 MB
  u16* Kp  = (u16*)d_out + NT;   // [B,S,D] bf16, 16 MB
  u16* Vpt = qb;                 // [B,H,DK,S] bf16 (qb dead after GEMM1)
  u16* Xp  = kb;                 // [B,S,D] bf16  (kb dead after GEMM2)

  const dim3 blk(256);
  // f32 -> bf16 conversions
  cvt_f32_bf16<<<dim3(4096), blk, 0, stream>>>(q, qb, (int)NT);
  cvt_f32_bf16<<<dim3(4096), blk, 0, stream>>>(k, kb, (int)NT);
  cvt_f32_bf16<<<dim3(4096), blk, 0, stream>>>(v, vb, (int)NT);
  cvt_f32_bf16<<<dim3(512),  blk, 0, stream>>>(Wq, Wqb, (int)NW);
  cvt_f32_bf16<<<dim3(512),  blk, 0, stream>>>(Wk, Wkb, (int)NW);
  cvt_f32_bf16<<<dim3(512),  blk, 0, stream>>>(Wv, Wvb, (int)NW);
  cvt_f32_bf16<<<dim3(512),  blk, 0, stream>>>(Wo, Wob, (int)NW);

  const dim3 ggrid(MTOT / 128, D_MODEL / 128);  // 64 x 8
  gemm_bt_bias<false, false><<<ggrid, blk, 0, stream>>>(qb, Wqb, bq, Qp);
  gemm_bt_bias<false, false><<<ggrid, blk, 0, stream>>>(kb, Wkb, bk, Kp);
  gemm_bt_bias<true,  false><<<ggrid, blk, 0, stream>>>(vb, Wvb, bv, Vpt);

  const dim3 agrid(SEQ / 128, BATCH * NUM_HEADS);  // 16 x 64
  attn_causal<<<agrid, blk, 0, stream>>>(Qp, Kp, Vpt, Xp);

  gemm_bt_bias<false, true><<<ggrid, blk, 0, stream>>>(Xp, Wob, bo, out);
}